// Round 1
// baseline (246.000 us; speedup 1.0000x reference)
//
#include <hip/hip_runtime.h>

#define EDIM 128

// Fast log_sigmoid: min(x,0) - log1p(exp(-|x|)) with hw exp/log.
// |log(1+t) - log1p(t)| contributes < 1e-7 absolute per term; the output is a
// mean over 786K terms, so the error is far below any sane tolerance.
__device__ __forceinline__ float fast_logsig(float x) {
    return fminf(x, 0.0f) - __logf(1.0f + __expf(-fabsf(x)));
}

// One wave handles 4 batch elements per iteration. All 64 lanes cooperate on
// every 128-float row (float2 per lane -> 512 B coalesced per row load, same
// as before). Indices are wave-uniform -> readfirstlane + int4 loads select
// s_load_dwordx4 (SMEM/lgkmcnt), decoupling the index fetch from the 28 row
// loads on vmcnt. Next iteration's indices are prefetched during compute.
__global__ __launch_bounds__(256) void sgns_loss_kernel(
    const float* __restrict__ second_emb,
    const float* __restrict__ context_emb,
    const int* __restrict__ v_i,
    const int* __restrict__ v_j,
    const int* __restrict__ negs,
    float* __restrict__ out,
    int B)
{
    const int tid    = blockIdx.x * blockDim.x + threadIdx.x;
    const int lane   = threadIdx.x & 63;
    const int gwave  = tid >> 6;
    const int nwaves = (gridDim.x * blockDim.x) >> 6;
    const int step   = nwaves * 4;

    const float2* __restrict__ se2 = (const float2*)second_emb;
    const float2* __restrict__ ce2 = (const float2*)context_emb;

    float acc = 0.0f;

    int base = gwave * 4;   // B % 4 == 0; elements base..base+3

#define LOAD_IDX(BB, VI, VJ, N0, N1, N2, N3, N4) do {            \
        const int ub_ = __builtin_amdgcn_readfirstlane(BB);      \
        VI = *(const int4*)(v_i + ub_);                          \
        VJ = *(const int4*)(v_j + ub_);                          \
        N0 = *(const int4*)(negs + 0 * (size_t)B + ub_);         \
        N1 = *(const int4*)(negs + 1 * (size_t)B + ub_);         \
        N2 = *(const int4*)(negs + 2 * (size_t)B + ub_);         \
        N3 = *(const int4*)(negs + 3 * (size_t)B + ub_);         \
        N4 = *(const int4*)(negs + 4 * (size_t)B + ub_);         \
    } while (0)

#define ROW(TBL, IDX) (TBL)[(((size_t)(uint32_t)(IDX)) << 6) + lane]

    if (base < B) {
        int4 cvi, cvj, cn0, cn1, cn2, cn3, cn4;
        LOAD_IDX(base, cvi, cvj, cn0, cn1, cn2, cn3, cn4);

        for (;;) {
            // ---- issue all 28 row loads (512 B each), element-major so the
            // vmcnt FIFO retires in consumption order ----
            const float2 a0  = ROW(se2, cvi.x);
            const float2 p0  = ROW(ce2, cvj.x);
            const float2 q00 = ROW(ce2, cn0.x);
            const float2 q01 = ROW(ce2, cn1.x);
            const float2 q02 = ROW(ce2, cn2.x);
            const float2 q03 = ROW(ce2, cn3.x);
            const float2 q04 = ROW(ce2, cn4.x);
            const float2 a1  = ROW(se2, cvi.y);
            const float2 p1  = ROW(ce2, cvj.y);
            const float2 q10 = ROW(ce2, cn0.y);
            const float2 q11 = ROW(ce2, cn1.y);
            const float2 q12 = ROW(ce2, cn2.y);
            const float2 q13 = ROW(ce2, cn3.y);
            const float2 q14 = ROW(ce2, cn4.y);
            const float2 a2  = ROW(se2, cvi.z);
            const float2 p2  = ROW(ce2, cvj.z);
            const float2 q20 = ROW(ce2, cn0.z);
            const float2 q21 = ROW(ce2, cn1.z);
            const float2 q22 = ROW(ce2, cn2.z);
            const float2 q23 = ROW(ce2, cn3.z);
            const float2 q24 = ROW(ce2, cn4.z);
            const float2 a3  = ROW(se2, cvi.w);
            const float2 p3  = ROW(ce2, cvj.w);
            const float2 q30 = ROW(ce2, cn0.w);
            const float2 q31 = ROW(ce2, cn1.w);
            const float2 q32 = ROW(ce2, cn2.w);
            const float2 q33 = ROW(ce2, cn3.w);
            const float2 q34 = ROW(ce2, cn4.w);

            // ---- prefetch next iteration's indices (SMEM path, overlaps
            // with the row loads in flight and the compute below) ----
            const int  nb   = base + step;
            const bool more = (nb < B);
            int4 nvi = cvi, nvj = cvj, nn0 = cn0, nn1 = cn1,
                 nn2 = cn2, nn3 = cn3, nn4 = cn4;
            if (more) LOAD_IDX(nb, nvi, nvj, nn0, nn1, nn2, nn3, nn4);

            // ---- 24 per-lane dot partials: D = 6e + s (s=0 pos, s=1..5 negs)
            float d[24];
            d[0]  = a0.x*p0.x  + a0.y*p0.y;
            d[1]  = a0.x*q00.x + a0.y*q00.y;
            d[2]  = a0.x*q01.x + a0.y*q01.y;
            d[3]  = a0.x*q02.x + a0.y*q02.y;
            d[4]  = a0.x*q03.x + a0.y*q03.y;
            d[5]  = a0.x*q04.x + a0.y*q04.y;
            d[6]  = a1.x*p1.x  + a1.y*p1.y;
            d[7]  = a1.x*q10.x + a1.y*q10.y;
            d[8]  = a1.x*q11.x + a1.y*q11.y;
            d[9]  = a1.x*q12.x + a1.y*q12.y;
            d[10] = a1.x*q13.x + a1.y*q13.y;
            d[11] = a1.x*q14.x + a1.y*q14.y;
            d[12] = a2.x*p2.x  + a2.y*p2.y;
            d[13] = a2.x*q20.x + a2.y*q20.y;
            d[14] = a2.x*q21.x + a2.y*q21.y;
            d[15] = a2.x*q22.x + a2.y*q22.y;
            d[16] = a2.x*q23.x + a2.y*q23.y;
            d[17] = a2.x*q24.x + a2.y*q24.y;
            d[18] = a3.x*p3.x  + a3.y*p3.y;
            d[19] = a3.x*q30.x + a3.y*q30.y;
            d[20] = a3.x*q31.x + a3.y*q31.y;
            d[21] = a3.x*q32.x + a3.y*q32.y;
            d[22] = a3.x*q33.x + a3.y*q33.y;
            d[23] = a3.x*q34.x + a3.y*q34.y;

            // ---- pair-merged butterfly: after step 1, even lanes carry dot
            // 2m, odd lanes carry dot 2m+1; the remaining 5 steps (xor 2..32)
            // preserve parity, so r[m] = S_{2m} in even lanes, S_{2m+1} in odd.
            float r[12];
            #pragma unroll
            for (int m = 0; m < 12; ++m) {
                const float e0 = d[2*m]     + __shfl_xor(d[2*m],     1);
                const float e1 = d[2*m + 1] + __shfl_xor(d[2*m + 1], 1);
                float mm = (lane & 1) ? e1 : e0;
                mm += __shfl_xor(mm, 2);
                mm += __shfl_xor(mm, 4);
                mm += __shfl_xor(mm, 8);
                mm += __shfl_xor(mm, 16);
                mm += __shfl_xor(mm, 32);
                r[m] = mm;
            }

            // ---- log-sigmoid on all lanes. Positive dots are D in
            // {0,6,12,18} = even D with m%3==0 (even lanes); every odd-lane
            // dot is a negative sample. Each dot is evaluated by the 32 lanes
            // of its parity class -> acc is over-counted exactly 32x.
            const bool odd = (lane & 1) != 0;
            #pragma unroll
            for (int m = 0; m < 12; ++m) {
                const float v = r[m];
                const float x = ((m % 3) == 0) ? (odd ? -v : v) : -v;
                acc += fast_logsig(x);
            }

            if (!more) break;
            base = nb;
            cvi = nvi; cvj = nvj;
            cn0 = nn0; cn1 = nn1; cn2 = nn2; cn3 = nn3; cn4 = nn4;
        }
    }

#undef ROW
#undef LOAD_IDX

    // ---- wave reduce, block reduce, one atomic per block ----
    #pragma unroll
    for (int off = 32; off >= 1; off >>= 1)
        acc += __shfl_xor(acc, off);

    __shared__ float wsum[4];
    const int wid = threadIdx.x >> 6;
    if ((threadIdx.x & 63) == 0) wsum[wid] = acc;
    __syncthreads();

    if (threadIdx.x == 0) {
        const float s = wsum[0] + wsum[1] + wsum[2] + wsum[3];
        // -mean, folding out the 32x over-count of each log-sigmoid term
        atomicAdd(out, s * (-1.0f / (32.0f * (float)B)));
    }
}

extern "C" void kernel_launch(void* const* d_in, const int* in_sizes, int n_in,
                              void* d_out, int out_size, void* d_ws, size_t ws_size,
                              hipStream_t stream) {
    const float* second_emb  = (const float*)d_in[0];
    const float* context_emb = (const float*)d_in[1];
    const int*   v_i  = (const int*)d_in[2];
    const int*   v_j  = (const int*)d_in[3];
    const int*   negs = (const int*)d_in[4];
    float* out = (float*)d_out;
    const int B = in_sizes[2];

    // d_out is re-poisoned before every timed launch; zero it first.
    hipMemsetAsync(d_out, 0, sizeof(float), stream);

    // 2048 blocks x 4 waves = 8192 waves; 4 elements/wave/iteration ->
    // 4 loop iterations per wave at B=131072.
    dim3 block(256);
    dim3 grid(2048);
    sgns_loss_kernel<<<grid, block, 0, stream>>>(
        second_emb, context_emb, v_i, v_j, negs, out, B);
}

// Round 2
// 241.650 us; speedup vs baseline: 1.0180x; 1.0180x over previous
//
#include <hip/hip_runtime.h>

#define EDIM 128

// Fast log_sigmoid: min(x,0) - log(1+exp(-|x|)) with hw v_exp_f32/v_log_f32.
// Absolute error < ~1e-6 per term; output is a mean over 786K terms.
__device__ __forceinline__ float fast_logsig(float x) {
    return fminf(x, 0.0f) - __logf(1.0f + __expf(-fabsf(x)));
}

// Half-wave (32 lanes) per batch element, 2 elements per half-wave per
// iteration (14 float4 row-loads in flight -> 512 B coalesced per row).
// Indices for the wave's 4 elements are wave-uniform -> readfirstlane +
// int4 loads select s_load_dwordx4 (SMEM/lgkmcnt path), decoupled from the
// row loads on vmcnt; next iteration's indices prefetch during compute.
__global__ __launch_bounds__(256) void sgns_loss_kernel(
    const float* __restrict__ second_emb,
    const float* __restrict__ context_emb,
    const int* __restrict__ v_i,
    const int* __restrict__ v_j,
    const int* __restrict__ negs,
    float* __restrict__ out,
    int B)
{
    const int tid    = blockIdx.x * blockDim.x + threadIdx.x;
    const int lane   = threadIdx.x & 63;
    const int half   = lane >> 5;   // 0/1: which element pair this half owns
    const int sub    = lane & 31;   // lane within the half-wave
    const int gwave  = tid >> 6;
    const int nwaves = (gridDim.x * blockDim.x) >> 6;
    const int step   = nwaves * 4;

    const float4* __restrict__ A = (const float4*)second_emb;   // 32 float4/row
    const float4* __restrict__ C = (const float4*)context_emb;

    float acc = 0.0f;

#define LOAD_IDX(BB, VI, VJ, N0, N1, N2, N3, N4) do {            \
        const int ub_ = __builtin_amdgcn_readfirstlane(BB);      \
        VI = *(const int4*)(v_i + ub_);                          \
        VJ = *(const int4*)(v_j + ub_);                          \
        N0 = *(const int4*)(negs + 0 * (size_t)B + ub_);         \
        N1 = *(const int4*)(negs + 1 * (size_t)B + ub_);         \
        N2 = *(const int4*)(negs + 2 * (size_t)B + ub_);         \
        N3 = *(const int4*)(negs + 3 * (size_t)B + ub_);         \
        N4 = *(const int4*)(negs + 4 * (size_t)B + ub_);         \
    } while (0)

#define ROW(TBL, IDX) (TBL)[(((size_t)(uint32_t)(IDX)) << 5) + sub]

    int base = gwave * 4;   // B % 4 == 0; elements base..base+3
    if (base < B) {
        int4 cvi, cvj, cn0, cn1, cn2, cn3, cn4;
        LOAD_IDX(base, cvi, cvj, cn0, cn1, cn2, cn3, cn4);

        for (;;) {
            // ---- select this half-wave's element pair (x,y for half 0;
            // z,w for half 1) -- 14 v_cndmask, no memory ops ----
            const int i0  = half ? cvi.z : cvi.x;
            const int i1  = half ? cvi.w : cvi.y;
            const int j0  = half ? cvj.z : cvj.x;
            const int j1  = half ? cvj.w : cvj.y;
            const int n00 = half ? cn0.z : cn0.x;
            const int n01 = half ? cn1.z : cn1.x;
            const int n02 = half ? cn2.z : cn2.x;
            const int n03 = half ? cn3.z : cn3.x;
            const int n04 = half ? cn4.z : cn4.x;
            const int n10 = half ? cn0.w : cn0.y;
            const int n11 = half ? cn1.w : cn1.y;
            const int n12 = half ? cn2.w : cn2.y;
            const int n13 = half ? cn3.w : cn3.y;
            const int n14 = half ? cn4.w : cn4.y;

            // ---- issue all 14 row loads, oldest-first in consumption order
            const float4 a0  = ROW(A, i0);
            const float4 p0  = ROW(C, j0);
            const float4 q00 = ROW(C, n00);
            const float4 q01 = ROW(C, n01);
            const float4 q02 = ROW(C, n02);
            const float4 q03 = ROW(C, n03);
            const float4 q04 = ROW(C, n04);
            const float4 a1  = ROW(A, i1);
            const float4 p1  = ROW(C, j1);
            const float4 q10 = ROW(C, n10);
            const float4 q11 = ROW(C, n11);
            const float4 q12 = ROW(C, n12);
            const float4 q13 = ROW(C, n13);
            const float4 q14 = ROW(C, n14);

            // ---- prefetch next iteration's indices (SMEM path; overlaps
            // the row loads in flight and the compute below) ----
            const int  nb   = base + step;
            const bool more = (nb < B);
            int4 nvi = cvi, nvj = cvj, nn0 = cn0, nn1 = cn1,
                 nn2 = cn2, nn3 = cn3, nn4 = cn4;
            if (more) LOAD_IDX(nb, nvi, nvj, nn0, nn1, nn2, nn3, nn4);

            // ---- 12 per-lane dot partials ----
            float d[12];
            d[0]  = a0.x * p0.x  + a0.y * p0.y  + a0.z * p0.z  + a0.w * p0.w;
            d[1]  = a0.x * q00.x + a0.y * q00.y + a0.z * q00.z + a0.w * q00.w;
            d[2]  = a0.x * q01.x + a0.y * q01.y + a0.z * q01.z + a0.w * q01.w;
            d[3]  = a0.x * q02.x + a0.y * q02.y + a0.z * q02.z + a0.w * q02.w;
            d[4]  = a0.x * q03.x + a0.y * q03.y + a0.z * q03.z + a0.w * q03.w;
            d[5]  = a0.x * q04.x + a0.y * q04.y + a0.z * q04.z + a0.w * q04.w;
            d[6]  = a1.x * p1.x  + a1.y * p1.y  + a1.z * p1.z  + a1.w * p1.w;
            d[7]  = a1.x * q10.x + a1.y * q10.y + a1.z * q10.z + a1.w * q10.w;
            d[8]  = a1.x * q11.x + a1.y * q11.y + a1.z * q11.z + a1.w * q11.w;
            d[9]  = a1.x * q12.x + a1.y * q12.y + a1.z * q12.z + a1.w * q12.w;
            d[10] = a1.x * q13.x + a1.y * q13.y + a1.z * q13.z + a1.w * q13.w;
            d[11] = a1.x * q14.x + a1.y * q14.y + a1.z * q14.z + a1.w * q14.w;

            // ---- butterfly reduce within each 32-lane half (offsets 1..16
            // keep bit 5 fixed); afterwards every lane of the half holds all
            // 12 full dot products ----
            #pragma unroll
            for (int off = 1; off <= 16; off <<= 1) {
                #pragma unroll
                for (int m = 0; m < 12; ++m)
                    d[m] += __shfl_xor(d[m], off);
            }

            // ---- distribute the 12 log_sigmoid evals: lanes 0..5 take
            // element b0 (dot s), lanes 8..13 take element b1 ----
            float x = 0.0f;
            bool active = false;
            if (sub < 6) {
                x = (sub == 0) ? d[0] : -d[sub];
                active = true;
            } else if (sub >= 8 && sub < 14) {
                const int s = sub - 8;
                x = (s == 0) ? d[6] : -d[6 + s];
                active = true;
            }
            if (active) acc += fast_logsig(x);

            if (!more) break;
            base = nb;
            cvi = nvi; cvj = nvj;
            cn0 = nn0; cn1 = nn1; cn2 = nn2; cn3 = nn3; cn4 = nn4;
        }
    }

#undef ROW
#undef LOAD_IDX

    // ---- wave reduce (both halves sum together), block reduce, one atomic
    #pragma unroll
    for (int off = 32; off >= 1; off >>= 1)
        acc += __shfl_xor(acc, off);

    __shared__ float wsum[4];
    const int wid = threadIdx.x >> 6;
    if ((threadIdx.x & 63) == 0) wsum[wid] = acc;
    __syncthreads();

    if (threadIdx.x == 0) {
        const float s = wsum[0] + wsum[1] + wsum[2] + wsum[3];
        atomicAdd(out, s * (-1.0f / (float)B));
    }
}

extern "C" void kernel_launch(void* const* d_in, const int* in_sizes, int n_in,
                              void* d_out, int out_size, void* d_ws, size_t ws_size,
                              hipStream_t stream) {
    const float* second_emb  = (const float*)d_in[0];
    const float* context_emb = (const float*)d_in[1];
    const int*   v_i  = (const int*)d_in[2];
    const int*   v_j  = (const int*)d_in[3];
    const int*   negs = (const int*)d_in[4];
    float* out = (float*)d_out;
    const int B = in_sizes[2];

    // d_out is re-poisoned before every timed launch; zero it first.
    hipMemsetAsync(d_out, 0, sizeof(float), stream);

    // 2048 blocks x 4 waves = 8192 waves = 32 waves/CU (full wave-slot
    // occupancy). Each wave covers 4 elements/iteration -> 4 iterations.
    dim3 block(256);
    dim3 grid(2048);
    sgns_loss_kernel<<<grid, block, 0, stream>>>(
        second_emb, context_emb, v_i, v_j, negs, out, B);
}